// Round 11
// baseline (47.709 us; speedup 1.0000x reference)
//
#include <hip/hip_runtime.h>

#define BINS 10

// ===== ELEM MATH: byte-for-byte from R2/R8/R10 (PASSED absmax 0.0). The
// algebraically-equivalent z-form (R3-R7) fails on HW (deterministic ~0.2
// error, unexplained) — do not reintroduce it without an A/B round.
// Scatter: register predicated adds (R1/R10, passed). Counts: packed u64.
__device__ __forceinline__ void ghm_elem(float x, float tt,
                                         unsigned long long& pk,
                                         float (&s)[BINS]) {
    float t = __expf(-fabsf(x));                 // e^{-|x|}
    float u = 1.f + t;
    float r = __builtin_amdgcn_rcpf(u);          // ~1ulp approx, ample slack
    float sig = (x >= 0.f) ? r : t * r;          // sigmoid(x), all ranges
    float d = sig - tt;
    int idx = (int)(fabsf(d) * 10.f);            // trunc (validated R8/R10)
    idx = idx < 9 ? idx : 9;
    pk += 1ull << (6 * idx);                     // packed counts, 6b/bin
    float bce = fmaxf(x, 0.f) - x * tt + __logf(u);  // log1p(e^{-|x|}) = log(u)
#pragma unroll
    for (int b = 0; b < BINS; ++b)               // 10x cmp+cndmask+add
        s[b] += (idx == b) ? bce : 0.f;
}

__device__ __forceinline__ void ghm_quad(float4 p, float4 t,
                                         unsigned long long& pk,
                                         float (&s)[BINS]) {
    ghm_elem(p.x, t.x, pk, s);
    ghm_elem(p.y, t.y, pk, s);
    ghm_elem(p.z, t.z, pk, s);
    ghm_elem(p.w, t.w, pk, s);
}

__global__ __launch_bounds__(256) void ghm_pass1(
    const float* __restrict__ pred, const float* __restrict__ tgt,
    long long n, int nb,
    float* __restrict__ bsum, int* __restrict__ bcnt)
{
    __shared__ float rsum[4][BINS];
    __shared__ int   rcnt[4][BINS];

    const int tid  = threadIdx.x;
    const int lane = tid & 63;
    const int wave = tid >> 6;

    float s[BINS];
#pragma unroll
    for (int b = 0; b < BINS; ++b) s[b] = 0.f;
    unsigned long long pk = 0;
    int c[BINS];
#pragma unroll
    for (int b = 0; b < BINS; ++b) c[b] = 0;

    const long long n4 = n >> 2;
    const float4* p4 = (const float4*)pred;
    const float4* t4 = (const float4*)tgt;

    // CHUNKED partitioning: block owns a contiguous quad range [q0, q1).
    // Within it, instruction k reads a 4KB-contiguous span (256 thr x 16B),
    // and the block walks its region sequentially -> long DRAM streams
    // (R10's strided layout presented ~4096 scattered 1KB streams; theory:
    // that is what capped consumption at ~2.5 TB/s).
    const long long qpb = (n4 + nb - 1) / nb;
    const long long q0  = (long long)blockIdx.x * qpb;
    const long long q1  = (q0 + qpb < n4) ? (q0 + qpb) : n4;

    int chunk = 0;
    for (long long i = q0 + tid; i < q1; i += 512) {   // unroll x2
        float4 pa = p4[i];
        float4 ta = t4[i];
        const long long j = i + 256;
        float4 pb, tb;
        const bool has2 = (j < q1);
        if (has2) { pb = p4[j]; tb = t4[j]; }          // issued with pa/ta
        ghm_quad(pa, ta, pk, s);
        if (has2) ghm_quad(pb, tb, pk, s);
        if (++chunk == 7) {              // 8 elems/iter x7 = 56 <= 63 per field
            chunk = 0;
#pragma unroll
            for (int b = 0; b < BINS; ++b) c[b] += (int)((pk >> (6 * b)) & 63u);
            pk = 0;
        }
    }
    const long long tail0 = n4 << 2;     // n % 4 remainder: block 0 (dead here)
    if (blockIdx.x == 0 && (long long)tid < (n - tail0))
        ghm_elem(pred[tail0 + tid], tgt[tail0 + tid], pk, s);
#pragma unroll
    for (int b = 0; b < BINS; ++b) c[b] += (int)((pk >> (6 * b)) & 63u);

    // block reduce: shuffle tree per bin, then cross-wave via LDS (validated)
#pragma unroll
    for (int b = 0; b < BINS; ++b) {
        float v = s[b];
        int   k = c[b];
        for (int off = 32; off; off >>= 1) {
            v += __shfl_down(v, off);
            k += __shfl_down(k, off);
        }
        if (lane == 0) { rsum[wave][b] = v; rcnt[wave][b] = k; }
    }
    __syncthreads();
    if (tid < BINS) {
        int b = tid;
        float v = rsum[0][b] + rsum[1][b] + rsum[2][b] + rsum[3][b];
        int   k = rcnt[0][b] + rcnt[1][b] + rcnt[2][b] + rcnt[3][b];
        bsum[(long long)b * nb + blockIdx.x] = v;   // bin-major partials
        bcnt[(long long)b * nb + blockIdx.x] = k;
    }
}

// 10 waves, one bin per wave: parallel strided loads, shuffle reduce.
// Byte-for-byte validated since R2.
__global__ __launch_bounds__(640) void ghm_pass2(
    const float* __restrict__ bsum, const int* __restrict__ bcnt,
    int nb, float* __restrict__ out)
{
    __shared__ double    ssum[BINS];
    __shared__ long long scnt[BINS];
    const int lane = threadIdx.x & 63;
    const int wave = threadIdx.x >> 6;   // 0..9 == bin

    double    acc = 0.0;
    long long cc  = 0;
    for (int i = lane; i < nb; i += 64) {
        acc += (double)bsum[(long long)wave * nb + i];
        cc  += (long long)bcnt[(long long)wave * nb + i];
    }
    for (int off = 32; off; off >>= 1) {
        acc += __shfl_down(acc, off);
        cc  += __shfl_down(cc, off);
    }
    if (lane == 0) { ssum[wave] = acc; scnt[wave] = cc; }
    __syncthreads();

    if (threadIdx.x == 0) {
        int n = 0;
#pragma unroll
        for (int b = 0; b < BINS; ++b) n += (scnt[b] > 0) ? 1 : 0;
        double loss = 0.0;
        if (n > 0) {
#pragma unroll
            for (int b = 0; b < BINS; ++b)
                if (scnt[b] > 0)
                    loss += ssum[b] / ((double)scnt[b] * (double)n);
        }
        out[0] = (float)loss;
    }
}

extern "C" void kernel_launch(void* const* d_in, const int* in_sizes, int n_in,
                              void* d_out, int out_size, void* d_ws, size_t ws_size,
                              hipStream_t stream) {
    const float* pred = (const float*)d_in[0];
    const float* tgt  = (const float*)d_in[1];
    float* out = (float*)d_out;
    const long long n = (long long)in_sizes[0];

    int nb = 2048;
    const size_t per_block = (size_t)BINS * (sizeof(float) + sizeof(int)); // 80 B
    while (nb > 1 && (size_t)nb * per_block > ws_size) nb >>= 1;

    float* bsum = (float*)d_ws;
    int*   bcnt = (int*)((char*)d_ws + (size_t)nb * BINS * sizeof(float));

    ghm_pass1<<<nb, 256, 0, stream>>>(pred, tgt, n, nb, bsum, bcnt);
    ghm_pass2<<<1, 640, 0, stream>>>(bsum, bcnt, nb, out);
}

// Round 13
// 46.886 us; speedup vs baseline: 1.0175x; 1.0175x over previous
//
#include <hip/hip_runtime.h>

#define BINS 10

typedef float f32x4 __attribute__((ext_vector_type(4)));  // native vec for nt-load

// ===== ELEM MATH: byte-for-byte from R2/R8/R10 (PASSED absmax 0.0). The
// algebraically-equivalent z-form (R3-R7) fails on HW (deterministic ~0.2
// error, unexplained) — do not reintroduce it without an A/B round.
// Scatter: register predicated adds (R1/R10, passed). Counts: packed u64.
__device__ __forceinline__ void ghm_elem(float x, float tt,
                                         unsigned long long& pk,
                                         float (&s)[BINS]) {
    float t = __expf(-fabsf(x));                 // e^{-|x|}
    float u = 1.f + t;
    float r = __builtin_amdgcn_rcpf(u);          // ~1ulp approx, ample slack
    float sig = (x >= 0.f) ? r : t * r;          // sigmoid(x), all ranges
    float d = sig - tt;
    int idx = (int)(fabsf(d) * 10.f);            // trunc (validated R8/R10)
    idx = idx < 9 ? idx : 9;
    pk += 1ull << (6 * idx);                     // packed counts, 6b/bin
    float bce = fmaxf(x, 0.f) - x * tt + __logf(u);  // log1p(e^{-|x|}) = log(u)
#pragma unroll
    for (int b = 0; b < BINS; ++b)               // 10x cmp+cndmask+add
        s[b] += (idx == b) ? bce : 0.f;
}

__device__ __forceinline__ void ghm_quad(f32x4 p, f32x4 t,
                                         unsigned long long& pk,
                                         float (&s)[BINS]) {
    ghm_elem(p.x, t.x, pk, s);
    ghm_elem(p.y, t.y, pk, s);
    ghm_elem(p.z, t.z, pk, s);
    ghm_elem(p.w, t.w, pk, s);
}

__global__ __launch_bounds__(256) void ghm_pass1(
    const float* __restrict__ pred, const float* __restrict__ tgt,
    long long n, int nb,
    float* __restrict__ bsum, int* __restrict__ bcnt)
{
    __shared__ float rsum[4][BINS];
    __shared__ int   rcnt[4][BINS];

    const int tid  = threadIdx.x;
    const int lane = tid & 63;
    const int wave = tid >> 6;

    float s[BINS];
#pragma unroll
    for (int b = 0; b < BINS; ++b) s[b] = 0.f;
    unsigned long long pk = 0;
    int c[BINS];
#pragma unroll
    for (int b = 0; b < BINS; ++b) c[b] = 0;

    const long long n4 = n >> 2;
    const f32x4* p4 = (const f32x4*)pred;
    const f32x4* t4 = (const f32x4*)tgt;

    // Chunked contiguous partitioning (R11) + NONTEMPORAL loads (R12 retry):
    // wall has been pinned at ~51us (2.5 TB/s delivered) across 4 rounds of
    // core-side changes; theory = the L3-serve path caps mixed L3+HBM
    // delivery. `nt` loads stream from HBM without cache allocation.
    const long long qpb = (n4 + nb - 1) / nb;
    const long long q0  = (long long)blockIdx.x * qpb;
    const long long q1  = (q0 + qpb < n4) ? (q0 + qpb) : n4;

    int chunk = 0;
    for (long long i = q0 + tid; i < q1; i += 512) {   // unroll x2
        f32x4 pa = __builtin_nontemporal_load(&p4[i]);
        f32x4 ta = __builtin_nontemporal_load(&t4[i]);
        const long long j = i + 256;
        f32x4 pb, tb;
        const bool has2 = (j < q1);
        if (has2) {
            pb = __builtin_nontemporal_load(&p4[j]);
            tb = __builtin_nontemporal_load(&t4[j]);
        }
        ghm_quad(pa, ta, pk, s);
        if (has2) ghm_quad(pb, tb, pk, s);
        if (++chunk == 7) {              // 8 elems/iter x7 = 56 <= 63 per field
            chunk = 0;
#pragma unroll
            for (int b = 0; b < BINS; ++b) c[b] += (int)((pk >> (6 * b)) & 63u);
            pk = 0;
        }
    }
    const long long tail0 = n4 << 2;     // n % 4 remainder: block 0
    if (blockIdx.x == 0 && (long long)tid < (n - tail0))
        ghm_elem(pred[tail0 + tid], tgt[tail0 + tid], pk, s);
#pragma unroll
    for (int b = 0; b < BINS; ++b) c[b] += (int)((pk >> (6 * b)) & 63u);

    // block reduce: shuffle tree per bin, then cross-wave via LDS (validated)
#pragma unroll
    for (int b = 0; b < BINS; ++b) {
        float v = s[b];
        int   k = c[b];
        for (int off = 32; off; off >>= 1) {
            v += __shfl_down(v, off);
            k += __shfl_down(k, off);
        }
        if (lane == 0) { rsum[wave][b] = v; rcnt[wave][b] = k; }
    }
    __syncthreads();
    if (tid < BINS) {
        int b = tid;
        float v = rsum[0][b] + rsum[1][b] + rsum[2][b] + rsum[3][b];
        int   k = rcnt[0][b] + rcnt[1][b] + rcnt[2][b] + rcnt[3][b];
        bsum[(long long)b * nb + blockIdx.x] = v;   // bin-major partials
        bcnt[(long long)b * nb + blockIdx.x] = k;
    }
}

// 10 waves, one bin per wave: parallel strided loads, shuffle reduce.
// Byte-for-byte validated since R2.
__global__ __launch_bounds__(640) void ghm_pass2(
    const float* __restrict__ bsum, const int* __restrict__ bcnt,
    int nb, float* __restrict__ out)
{
    __shared__ double    ssum[BINS];
    __shared__ long long scnt[BINS];
    const int lane = threadIdx.x & 63;
    const int wave = threadIdx.x >> 6;   // 0..9 == bin

    double    acc = 0.0;
    long long cc  = 0;
    for (int i = lane; i < nb; i += 64) {
        acc += (double)bsum[(long long)wave * nb + i];
        cc  += (long long)bcnt[(long long)wave * nb + i];
    }
    for (int off = 32; off; off >>= 1) {
        acc += __shfl_down(acc, off);
        cc  += __shfl_down(cc, off);
    }
    if (lane == 0) { ssum[wave] = acc; scnt[wave] = cc; }
    __syncthreads();

    if (threadIdx.x == 0) {
        int n = 0;
#pragma unroll
        for (int b = 0; b < BINS; ++b) n += (scnt[b] > 0) ? 1 : 0;
        double loss = 0.0;
        if (n > 0) {
#pragma unroll
            for (int b = 0; b < BINS; ++b)
                if (scnt[b] > 0)
                    loss += ssum[b] / ((double)scnt[b] * (double)n);
        }
        out[0] = (float)loss;
    }
}

extern "C" void kernel_launch(void* const* d_in, const int* in_sizes, int n_in,
                              void* d_out, int out_size, void* d_ws, size_t ws_size,
                              hipStream_t stream) {
    const float* pred = (const float*)d_in[0];
    const float* tgt  = (const float*)d_in[1];
    float* out = (float*)d_out;
    const long long n = (long long)in_sizes[0];

    int nb = 2048;
    const size_t per_block = (size_t)BINS * (sizeof(float) + sizeof(int)); // 80 B
    while (nb > 1 && (size_t)nb * per_block > ws_size) nb >>= 1;

    float* bsum = (float*)d_ws;
    int*   bcnt = (int*)((char*)d_ws + (size_t)nb * BINS * sizeof(float));

    ghm_pass1<<<nb, 256, 0, stream>>>(pred, tgt, n, nb, bsum, bcnt);
    ghm_pass2<<<1, 640, 0, stream>>>(bsum, bcnt, nb, out);
}